// Round 6
// baseline (265.368 us; speedup 1.0000x reference)
//
#include <hip/hip_runtime.h>

#define H 1024
#define W 1024
#define NIMG 8
#define CPT 4                   // columns per thread
#define TH 8                    // output rows per wave-tile (16 waves/CU; round-5
                                // A/B: 32 waves/CU gave ZERO extra hiding, +30% work)
#define NBX 4                   // x-quadrants: 64 lanes * 4 cols * 4 = 1024
#define WPB 4                   // waves per block, stacked in y
#define NBY (H / (TH * WPB))    // 32
#define NBLK (NBX * NBY * NIMG) // 1024 blocks = 4 blocks/CU
#define NWAVES (NBLK * WPB)     // 4096
#define EPS 1e-5f

struct RS { float I[CPT], J[CPT], II[CPT], JJ[CPT], IJ[CPT]; };

// ---- depth-1 software prefetch, spill-safe form ----
// Named float4 locals only (no structs across iterations, no runtime-indexed
// arrays, no aggregate ternaries) + fully unrolled call sites, so everything
// stays in VGPRs. Round-1/3 spills came from violating exactly this.
__device__ __forceinline__ void pf_row(const float* __restrict__ Ip,
                                       const float* __restrict__ Jp,
                                       int r, int X, bool okL, bool okR,
                                       float4& Il, float4& Ic, float4& Ir,
                                       float4& Jl, float4& Jc, float4& Jr) {
  const int rc = min(max(r, 0), H - 1);       // clamped addr; consume re-guards
  const float* Irow = Ip + (size_t)rc * W;
  const float* Jrow = Jp + (size_t)rc * W;
  const float4 z = make_float4(0.f, 0.f, 0.f, 0.f);
  Ic = *reinterpret_cast<const float4*>(Irow + X);
  Jc = *reinterpret_cast<const float4*>(Jrow + X);
  if (okL) {
    Il = *reinterpret_cast<const float4*>(Irow + X - 4);
    Jl = *reinterpret_cast<const float4*>(Jrow + X - 4);
  } else { Il = z; Jl = z; }
  if (okR) {
    Ir = *reinterpret_cast<const float4*>(Irow + X + 4);
    Jr = *reinterpret_cast<const float4*>(Jrow + X + 4);
  } else { Ir = z; Jr = z; }
}

// Horizontal 9-box rowsums for 4 output cols from 12 already-loaded px.
__device__ __forceinline__ void rowsums(const float4& Il, const float4& Ic,
                                        const float4& Ir, const float4& Jl,
                                        const float4& Jc, const float4& Jr,
                                        RS& o) {
  const float a[12] = {Il.x, Il.y, Il.z, Il.w, Ic.x, Ic.y, Ic.z, Ic.w,
                       Ir.x, Ir.y, Ir.z, Ir.w};
  const float b[12] = {Jl.x, Jl.y, Jl.z, Jl.w, Jc.x, Jc.y, Jc.z, Jc.w,
                       Jr.x, Jr.y, Jr.z, Jr.w};
  float sI=0.f, sJ=0.f, sII=0.f, sJJ=0.f, sIJ=0.f;
  #pragma unroll
  for (int k = 0; k < 9; ++k) {
    sI += a[k]; sJ += b[k];
    sII = fmaf(a[k], a[k], sII);
    sJJ = fmaf(b[k], b[k], sJJ);
    sIJ = fmaf(a[k], b[k], sIJ);
  }
  o.I[0]=sI; o.J[0]=sJ; o.II[0]=sII; o.JJ[0]=sJJ; o.IJ[0]=sIJ;
  #pragma unroll
  for (int i = 1; i < CPT; ++i) {
    float an=a[i+8], al=a[i-1], bn=b[i+8], bl=b[i-1];
    sI += an - al;  sJ += bn - bl;
    sII = fmaf(-al, al, fmaf(an, an, sII));
    sJJ = fmaf(-bl, bl, fmaf(bn, bn, sJJ));
    sIJ = fmaf(-al, bl, fmaf(an, bn, sIJ));
    o.I[i]=sI; o.J[i]=sJ; o.II[i]=sII; o.JJ[i]=sJJ; o.IJ[i]=sIJ;
  }
}

// No LDS, no barriers. Each wave walks a 256-col x 8-row tile; per-thread
// 4-col strip with vertical running window sums in registers.
// First-touch rows (warm-up + entering, 16 total) are register-prefetched one
// iteration ahead (~550 cy of independent work between load issue and use ->
// covers most of the ~900 cy HBM miss). Leaving rows re-load direct (L1-hot).
// Evidence log: TLP 16->32 waves/CU = no gain (r5); shuffle-halo (L1 traffic
// /3) = neutral (r4); tight launch_bounds caps -> scratch spill (r1/r3).
__global__ __launch_bounds__(256, 4)
void ncc_main(const float* __restrict__ I, const float* __restrict__ J,
              float* __restrict__ partial) {
  const int tid  = threadIdx.x;
  const int lane = tid & 63, wv = tid >> 6;
  // XCD-bijective remap (NBLK = 1024 = 8 * 128): XCD k (= bid % 8) processes
  // exactly image k -> halo re-reads stay in one XCD's L2.
  const int bid  = (int)blockIdx.x;
  const int tile = ((bid & 7) << 7) | (bid >> 3);
  const int bx   = tile & (NBX - 1);
  const int rest = tile / NBX;            // [0, 256)
  const int by   = rest & (NBY - 1);
  const int bz   = rest / NBY;            // image index == XCD id
  const int X  = bx * 256 + lane * CPT;
  const int y0 = (by * WPB + wv) * TH;
  const bool okL = (X >= 4);
  const bool okR = (X + 8 <= W);
  const size_t img_off = (size_t)bz * H * W;
  const float* Ip = I + img_off;
  const float* Jp = J + img_off;

  float wI[CPT], wJ[CPT], wII[CPT], wJJ[CPT], wIJ[CPT];
  #pragma unroll
  for (int i = 0; i < CPT; ++i) { wI[i]=wJ[i]=wII[i]=wJJ[i]=wIJ[i]=0.f; }
  float acc = 0.f;
  const float inv81 = 1.0f / 81.0f;

  // consume a staged (prefetched) row: always an entering row (+)
  auto apply_staged = [&](int r, const float4& Il, const float4& Ic,
                          const float4& Ir, const float4& Jl,
                          const float4& Jc, const float4& Jr) {
    if ((unsigned)r < (unsigned)H) {      // wave-uniform guard
      RS o; rowsums(Il, Ic, Ir, Jl, Jc, Jr, o);
      #pragma unroll
      for (int i = 0; i < CPT; ++i) {
        wI[i] += o.I[i]; wJ[i] += o.J[i]; wII[i] += o.II[i];
        wJJ[i] += o.JJ[i]; wIJ[i] += o.IJ[i];
      }
    }
  };
  // leaving row: direct loads (touched ~2 iterations ago, L1/L2-hot)
  auto apply_leave = [&](int r) {
    if ((unsigned)r < (unsigned)H) {
      float4 Il, Ic, Ir, Jl, Jc, Jr;
      pf_row(Ip, Jp, r, X, okL, okR, Il, Ic, Ir, Jl, Jc, Jr);
      RS o; rowsums(Il, Ic, Ir, Jl, Jc, Jr, o);
      #pragma unroll
      for (int i = 0; i < CPT; ++i) {
        wI[i] -= o.I[i]; wJ[i] -= o.J[i]; wII[i] -= o.II[i];
        wJJ[i] -= o.JJ[i]; wIJ[i] -= o.IJ[i];
      }
    }
  };
  auto emit = [&]() {
    #pragma unroll
    for (int i = 0; i < CPT; ++i) {
      float cross = fmaf(-(wI[i] * wJ[i]), inv81, wIJ[i]);
      float Iv    = fmaf(-(wI[i] * wI[i]), inv81, wII[i]);
      float Jv    = fmaf(-(wJ[i] * wJ[i]), inv81, wJJ[i]);
      acc = fmaf(cross * cross,
                 __builtin_amdgcn_rcpf(fmaf(Iv, Jv, EPS)), acc);
    }
  };

  // staged-row sequence R(k) = y0-4+k, k = 0..15 (9 warm-up + 7 entering)
  float4 cIl, cIc, cIr, cJl, cJc, cJr;    // current staged row
  float4 nIl, nIc, nIr, nJl, nJc, nJr;    // next staged row (in flight)
  pf_row(Ip, Jp, y0 - 4, X, okL, okR, cIl, cIc, cIr, cJl, cJc, cJr);

  // warm-up: consume R(0..8) = rows y0-4..y0+4, always one row in flight
  #pragma unroll
  for (int k = 0; k < 9; ++k) {
    pf_row(Ip, Jp, y0 - 3 + k, X, okL, okR, nIl, nIc, nIr, nJl, nJc, nJr);
    apply_staged(y0 - 4 + k, cIl, cIc, cIr, cJl, cJc, cJr);
    cIl = nIl; cIc = nIc; cIr = nIr; cJl = nJl; cJc = nJc; cJr = nJr;
  }
  emit();                                  // window = rows y0-4..y0+4

  // steady state: prefetch next entering row, do leaving-row work in the
  // latency shadow, then consume the current entering row.
  #pragma unroll
  for (int k = 0; k < TH - 1; ++k) {
    if (k < TH - 2)
      pf_row(Ip, Jp, y0 + 6 + k, X, okL, okR, nIl, nIc, nIr, nJl, nJc, nJr);
    apply_leave(y0 - 4 + k);              // independent work, hides pf latency
    apply_staged(y0 + 5 + k, cIl, cIc, cIr, cJl, cJc, cJr);
    emit();
    cIl = nIl; cIc = nIc; cIr = nIr; cJl = nJl; cJc = nJc; cJr = nJr;
  }

  // wave reduction -> one partial per wave (no LDS, no barrier)
  #pragma unroll
  for (int off = 32; off > 0; off >>= 1)
    acc += __shfl_down(acc, off, 64);
  if (lane == 0)
    partial[tile * WPB + wv] = acc;
}

__global__ __launch_bounds__(256)
void ncc_reduce(const float* __restrict__ partial, float* __restrict__ out) {
  __shared__ float red[4];
  const int tid = threadIdx.x;
  const float4* p4 = reinterpret_cast<const float4*>(partial);
  float s = 0.f;
  #pragma unroll
  for (int i = tid; i < NWAVES / 4; i += 256) {
    float4 v = p4[i];
    s += (v.x + v.y) + (v.z + v.w);
  }
  #pragma unroll
  for (int off = 32; off > 0; off >>= 1)
    s += __shfl_down(s, off, 64);
  if ((tid & 63) == 0) red[tid >> 6] = s;
  __syncthreads();
  if (tid == 0)
    out[0] = (red[0] + red[1] + red[2] + red[3]) *
             (1.0f / (float)((size_t)NIMG * H * W));
}

extern "C" void kernel_launch(void* const* d_in, const int* in_sizes, int n_in,
                              void* d_out, int out_size, void* d_ws, size_t ws_size,
                              hipStream_t stream) {
  const float* I = (const float*)d_in[0];
  const float* J = (const float*)d_in[1];
  float* out     = (float*)d_out;
  float* partial = (float*)d_ws;            // 4096 * 4 B = 16 KB

  hipLaunchKernelGGL(ncc_main, dim3(NBLK), dim3(256), 0, stream, I, J, partial);
  hipLaunchKernelGGL(ncc_reduce, dim3(1), dim3(256), 0, stream, partial, out);
}